// Round 7
// baseline (136.583 us; speedup 1.0000x reference)
//
#include <hip/hip_runtime.h>
#include <math.h>

#define BB 8
#define TT 2048
#define FF 67
#define DD 64
#define BT (BB * TT)
#define JITTER 1e-6f

#define NT 32                  // 64-wide tiles per dim
#define NOFF 496               // strict-lower tiles per batch
#define NOFFB (BB * NOFF)      // 3968 off-diag blocks (first)
#define NBLK (NOFFB + BB * NT) // + 256 diag blocks (tail) = 4224

// ---------------- kernel A: pack scaled z (f32) + per-row stats --------------
__global__ __launch_bounds__(256) void pack_stats_kernel(
    const float* __restrict__ in, float* __restrict__ out_mean,
    float* __restrict__ c, float* __restrict__ noise,
    float4* __restrict__ zp4) {
  int g = blockIdx.x * 256 + threadIdx.x;   // 0 .. BT*16-1
  int row = g >> 4, dc = g & 15;
  const float* p = in + (size_t)row * FF + 1 + dc * 4;
  float z0 = p[0] * 0.125f, z1 = p[1] * 0.125f;
  float z2 = p[2] * 0.125f, z3 = p[3] * 0.125f;
  zp4[(size_t)row * 16 + dc] = make_float4(z0, z1, z2, z3);
  float sq = z0 * z0 + z1 * z1 + z2 * z2 + z3 * z3;
  sq += __shfl_xor(sq, 1);
  sq += __shfl_xor(sq, 2);
  sq += __shfl_xor(sq, 4);
  sq += __shfl_xor(sq, 8);
  if (dc == 0) {
    const float* r = in + (size_t)row * FF;
    out_mean[row] = r[0];
    float v = r[1 + DD];
    float x = r[1 + DD + 1];
    float sp = fmaxf(x, 0.f) + log1pf(__expf(-fabsf(x)));
    c[row] = v * __expf(-0.5f * sq);
    noise[row] = sp;
  }
}

// ---------------- fallback per-row stats (small ws) --------------------------
__global__ __launch_bounds__(256) void row_stats_kernel(
    const float* __restrict__ in, float* __restrict__ out_mean,
    float* __restrict__ c, float* __restrict__ noise) {
  int idx = blockIdx.x * 256 + threadIdx.x;
  if (idx >= BT) return;
  const float* row = in + (size_t)idx * FF;
  out_mean[idx] = row[0];
  float sq = 0.f;
#pragma unroll
  for (int d = 0; d < DD; ++d) {
    float z = row[1 + d] * 0.125f;
    sq = fmaf(z, z, sq);
  }
  float v = row[1 + DD];
  float x = row[1 + DD + 1];
  float sp = fmaxf(x, 0.f) + log1pf(__expf(-fabsf(x)));
  c[idx] = v * __expf(-0.5f * sq);
  noise[idx] = sp;
}

// ---------------- kernel B: one-shot 64x64 triangular tiles ------------------
// 32 KB LDS (two 64x64 f32 panels, sw=(row>>2)&7 XOR swizzle) -> 5 blocks/CU.
// Mirror tile staged via LDS transpose (aliases dead A panel) so ALL output
// stores are full-line coalesced float4. Plain (cached) stores — R6's
// nontemporal stores regressed 86->128us; this round isolates that variable.
template <bool PACKED>
__global__ __launch_bounds__(256) void cov_kernel(
    const float* __restrict__ in, const float4* __restrict__ zp4,
    const float* __restrict__ c, const float* __restrict__ noise,
    float* __restrict__ out_f, float* __restrict__ out_y) {
  __shared__ float4 lds[2048];   // A: [0..1023], B: [1024..2047]; ft aliases A

  // decode block -> (b, ti, tj); batch-major so neighbors share the i-panel
  int wid = blockIdx.x;
  int b, ti, tj;
  if (wid < NOFFB) {
    b = wid / NOFF;
    int k = wid - b * NOFF;          // k = ti*(ti-1)/2 + tj, tj < ti
    int x = (int)((1.0f + sqrtf(1.0f + 8.0f * (float)k)) * 0.5f);
    while (x * (x - 1) / 2 > k) --x;
    while ((x + 1) * x / 2 <= k) ++x;
    ti = x;
    tj = k - x * (x - 1) / 2;
  } else {
    int r = wid - NOFFB;
    b = r >> 5;
    ti = tj = r & 31;
  }
  const bool diag = (ti == tj);
  const int gi0 = ti * 64, gj0 = tj * 64;
  const int t = threadIdx.x;

  // ---- stage panels (sw=(row>>2)&7) ----
#pragma unroll
  for (int kk = 0; kk < 4; ++kk) {
    int idx = kk * 256 + t;
    int row = idx >> 4, ch = idx & 15;
    int sw = (row >> 2) & 7;
    float4 av, bv;
    if (PACKED) {
      av = zp4[(size_t)(b * TT + gi0 + row) * 16 + ch];
      bv = zp4[(size_t)(b * TT + gj0 + row) * 16 + ch];
    } else {
      const float* pi = in + (size_t)(b * TT + gi0 + row) * FF + 1 + ch * 4;
      const float* pj = in + (size_t)(b * TT + gj0 + row) * FF + 1 + ch * 4;
      av = make_float4(pi[0] * 0.125f, pi[1] * 0.125f, pi[2] * 0.125f,
                       pi[3] * 0.125f);
      bv = make_float4(pj[0] * 0.125f, pj[1] * 0.125f, pj[2] * 0.125f,
                       pj[3] * 0.125f);
    }
    lds[row * 16 + (ch ^ sw)] = av;
    lds[1024 + row * 16 + (ch ^ sw)] = bv;
  }
  __syncthreads();

  const int tx = t & 15, ty = t >> 4;
  const int i0 = ty * 4, j0 = tx * 4;
  const int swi = ty & 7, swj = tx & 7;

  // ---- 4x4 micro-tile over 16 float4 d-chunks ----
  float acc[4][4] = {};
#pragma unroll
  for (int dc = 0; dc < 16; ++dc) {
    float4 af[4], bf[4];
#pragma unroll
    for (int a = 0; a < 4; ++a) af[a] = lds[(i0 + a) * 16 + (dc ^ swi)];
#pragma unroll
    for (int q = 0; q < 4; ++q)
      bf[q] = lds[1024 + (j0 + q) * 16 + (dc ^ swj)];
#pragma unroll
    for (int a = 0; a < 4; ++a)
#pragma unroll
      for (int q = 0; q < 4; ++q) {
        acc[a][q] = fmaf(af[a].x, bf[q].x, acc[a][q]);
        acc[a][q] = fmaf(af[a].y, bf[q].y, acc[a][q]);
        acc[a][q] = fmaf(af[a].z, bf[q].z, acc[a][q]);
        acc[a][q] = fmaf(af[a].w, bf[q].w, acc[a][q]);
      }
  }

  // ---- f = exp(acc)*ci*cj ----
  const float* cbp = c + b * TT;
  float ci[4], cj[4];
#pragma unroll
  for (int a = 0; a < 4; ++a) ci[a] = cbp[gi0 + i0 + a];
#pragma unroll
  for (int q = 0; q < 4; ++q) cj[q] = cbp[gj0 + j0 + q];
#pragma unroll
  for (int a = 0; a < 4; ++a)
#pragma unroll
    for (int q = 0; q < 4; ++q)
      acc[a][q] = __expf(acc[a][q]) * ci[a] * cj[q];

  const size_t TTT = (size_t)TT * TT;
  const size_t obase = (size_t)b * TTT;

  // ---- direct tile: full-line coalesced stores ----
#pragma unroll
  for (int a = 0; a < 4; ++a) {
    int gi = gi0 + i0 + a;
    float fv[4], yv[4];
#pragma unroll
    for (int q = 0; q < 4; ++q) {
      float ff = acc[a][q];
      float yy = ff;
      if (diag && (i0 + a == j0 + q)) {
        ff += JITTER;
        yy = ff + noise[b * TT + gi];
      }
      fv[q] = ff;
      yv[q] = yy;
    }
    size_t off = obase + (size_t)gi * TT + gj0 + j0;
    *reinterpret_cast<float4*>(out_f + off) =
        make_float4(fv[0], fv[1], fv[2], fv[3]);
    *reinterpret_cast<float4*>(out_y + off) =
        make_float4(yv[0], yv[1], yv[2], yv[3]);
  }

  // ---- mirror tile (off-diag): LDS transpose -> full-line stores ----
  if (!diag) {
    __syncthreads();   // panel A reads done everywhere
    // ft[j][i] as [64 rows][16 f4], sw=(row>>2)&7; thread writes float4 over a
#pragma unroll
    for (int q = 0; q < 4; ++q) {
      int jr = j0 + q;                       // row of ft = column of tile
      int sw = tx & 7;                       // (jr>>2)&7 == tx&7
      lds[jr * 16 + ((ty) ^ sw)] =           // chunk index over i = ty
          make_float4(acc[0][q], acc[1][q], acc[2][q], acc[3][q]);
    }
    __syncthreads();
#pragma unroll
    for (int kk = 0; kk < 4; ++kk) {
      int idx = kk * 256 + t;
      int jr = idx >> 4, kc = idx & 15;
      int sw = (jr >> 2) & 7;
      float4 v = lds[jr * 16 + (kc ^ sw)];
      size_t off = obase + (size_t)(gj0 + jr) * TT + gi0 + kc * 4;
      *reinterpret_cast<float4*>(out_f + off) = v;
      *reinterpret_cast<float4*>(out_y + off) = v;
    }
  }
}

extern "C" void kernel_launch(void* const* d_in, const int* in_sizes, int n_in,
                              void* d_out, int out_size, void* d_ws,
                              size_t ws_size, hipStream_t stream) {
  const float* in = (const float*)d_in[0];
  float* out = (float*)d_out;
  float* c = (float*)d_ws;                              // BT floats
  float* noise = c + BT;                                // BT floats
  float4* zp4 = (float4*)((char*)d_ws + (size_t)2 * BT * 4);  // BT*DD f32
  float* out_mean = out;                                // BT
  float* out_f = out + BT;                              // BB*TT*TT
  float* out_y = out_f + (size_t)BB * TT * TT;

  const size_t need = (size_t)2 * BT * 4 + (size_t)BT * DD * 4;
  if (ws_size >= need) {
    pack_stats_kernel<<<(BT * 16) / 256, 256, 0, stream>>>(in, out_mean, c,
                                                           noise, zp4);
    cov_kernel<true><<<NBLK, 256, 0, stream>>>(in, zp4, c, noise, out_f,
                                               out_y);
  } else {
    row_stats_kernel<<<BT / 256, 256, 0, stream>>>(in, out_mean, c, noise);
    cov_kernel<false><<<NBLK, 256, 0, stream>>>(in, zp4, c, noise, out_f,
                                                out_y);
  }
}

// Round 8
// 61.141 us; speedup vs baseline: 2.2339x; 2.2339x over previous
//
#include <hip/hip_runtime.h>
#include <math.h>

#define BB 8
#define TT 2048
#define FF 67
#define DD 64
#define BT (BB * TT)
#define JITTER 1e-6f

#define NT 32                  // 64-wide tiles per dim
#define NOFF 496               // strict-lower tiles per batch
#define NOFFB (BB * NOFF)      // 3968 off-diag blocks (first)
#define NBLK (NOFFB + BB * NT) // + 256 diag blocks (tail) = 4224

// ---- bf16 helpers (manual RNE pack, shift/and unpack) -----------------------
__device__ __forceinline__ unsigned int f2bf(float f) {
  unsigned int u = __float_as_uint(f);
  return (u + 0x7fffu + ((u >> 16) & 1u)) >> 16;
}
__device__ __forceinline__ float bf_lo(unsigned int u) {
  return __uint_as_float(u << 16);
}
__device__ __forceinline__ float bf_hi(unsigned int u) {
  return __uint_as_float(u & 0xffff0000u);
}

// ---------------- kernel A: pack z->bf16 + per-row stats ---------------------
// 8 lanes per row; each packs 8 d's (d = dc*8..dc*8+7) into one uint4.
__global__ __launch_bounds__(256) void pack_stats_kernel(
    const float* __restrict__ in, float* __restrict__ out_mean,
    float* __restrict__ c, float* __restrict__ noise,
    uint4* __restrict__ zp4) {
  int g = blockIdx.x * 256 + threadIdx.x;   // 0 .. BT*8-1
  int row = g >> 3, dc = g & 7;
  const float* p = in + (size_t)row * FF + 1 + dc * 8;
  float sq = 0.f;
  unsigned int w[4];
#pragma unroll
  for (int k = 0; k < 4; ++k) {
    float a = p[2 * k] * 0.125f;
    float b2 = p[2 * k + 1] * 0.125f;
    sq += a * a + b2 * b2;
    w[k] = f2bf(a) | (f2bf(b2) << 16);
  }
  uint4 pk;
  pk.x = w[0]; pk.y = w[1]; pk.z = w[2]; pk.w = w[3];
  zp4[(size_t)row * 8 + dc] = pk;
  sq += __shfl_xor(sq, 1);
  sq += __shfl_xor(sq, 2);
  sq += __shfl_xor(sq, 4);
  if (dc == 0) {
    const float* r = in + (size_t)row * FF;
    out_mean[row] = r[0];
    float v = r[1 + DD];
    float x = r[1 + DD + 1];
    float sp = fmaxf(x, 0.f) + log1pf(__expf(-fabsf(x)));
    c[row] = v * __expf(-0.5f * sq);
    noise[row] = sp;
  }
}

// ---------------- fallback per-row stats (small ws) --------------------------
__global__ __launch_bounds__(256) void row_stats_kernel(
    const float* __restrict__ in, float* __restrict__ out_mean,
    float* __restrict__ c, float* __restrict__ noise) {
  int idx = blockIdx.x * 256 + threadIdx.x;
  if (idx >= BT) return;
  const float* row = in + (size_t)idx * FF;
  out_mean[idx] = row[0];
  float sq = 0.f;
#pragma unroll
  for (int d = 0; d < DD; ++d) {
    float z = row[1 + d] * 0.125f;
    sq = fmaf(z, z, sq);
  }
  float v = row[1 + DD];
  float x = row[1 + DD + 1];
  float sp = fmaxf(x, 0.f) + log1pf(__expf(-fabsf(x)));
  c[idx] = v * __expf(-0.5f * sq);
  noise[idx] = sp;
}

// bf16 dot over one uint4 word: acc[a][q] += a_lo*b_lo + a_hi*b_hi
#define DOT_WORD(WX)                                                    \
  {                                                                     \
    float fa0[4], fa1[4], fb0[4], fb1[4];                               \
    _Pragma("unroll") for (int a = 0; a < 4; ++a) {                     \
      fa0[a] = bf_lo(ai[a].WX);                                         \
      fa1[a] = bf_hi(ai[a].WX);                                         \
    }                                                                   \
    _Pragma("unroll") for (int q = 0; q < 4; ++q) {                     \
      fb0[q] = bf_lo(bj[q].WX);                                         \
      fb1[q] = bf_hi(bj[q].WX);                                         \
    }                                                                   \
    _Pragma("unroll") for (int a = 0; a < 4; ++a)                       \
        _Pragma("unroll") for (int q = 0; q < 4; ++q) acc[a][q] =       \
        fmaf(fa0[a], fb0[q], fmaf(fa1[a], fb1[q], acc[a][q]));          \
  }

// ---------------- kernel B: 64x64 tiles, bf16 panels, stores LAST ------------
// LDS 16 KB: bf16 A panel [0..511], B panel [512..1023] (uint4 units).
// After compute the f32 mirror tile (16 KB) aliases both panels. ALL barriers
// precede ALL global stores (compiler drains vmcnt at barriers -> a barrier
// after stores serializes store-drain per block; R4-R7's hidden cost).
template <bool PACKED>
__global__ __launch_bounds__(256, 4) void cov_kernel(
    const float* __restrict__ in, const uint4* __restrict__ zp4,
    const float* __restrict__ c, const float* __restrict__ noise,
    float* __restrict__ out_f, float* __restrict__ out_y) {
  __shared__ uint4 lds[1024];   // 16 KB

  // decode block -> (b, ti, tj); off-diag batch-major first, diag tail
  int wid = blockIdx.x;
  int b, ti, tj;
  if (wid < NOFFB) {
    b = wid / NOFF;
    int k = wid - b * NOFF;          // k = ti*(ti-1)/2 + tj, tj < ti
    int x = (int)((1.0f + sqrtf(1.0f + 8.0f * (float)k)) * 0.5f);
    while (x * (x - 1) / 2 > k) --x;
    while ((x + 1) * x / 2 <= k) ++x;
    ti = x;
    tj = k - x * (x - 1) / 2;
  } else {
    int r = wid - NOFFB;
    b = r >> 5;
    ti = tj = r & 31;
  }
  const bool diag = (ti == tj);
  const int gi0 = ti * 64, gj0 = tj * 64;
  const int t = threadIdx.x;

  // ---- stage bf16 panels; swizzle sw=(row>>2)&7 on 8-chunk index ----
#pragma unroll
  for (int kk = 0; kk < 2; ++kk) {
    int idx = kk * 256 + t;
    int row = idx >> 3, ch = idx & 7;
    int sw = (row >> 2) & 7;
    uint4 av, bv;
    if (PACKED) {
      av = zp4[(size_t)(b * TT + gi0 + row) * 8 + ch];
      bv = zp4[(size_t)(b * TT + gj0 + row) * 8 + ch];
    } else {
      const float* pi = in + (size_t)(b * TT + gi0 + row) * FF + 1 + ch * 8;
      const float* pj = in + (size_t)(b * TT + gj0 + row) * FF + 1 + ch * 8;
      unsigned int wi[4], wj[4];
#pragma unroll
      for (int e = 0; e < 4; ++e) {
        wi[e] = f2bf(pi[2 * e] * 0.125f) | (f2bf(pi[2 * e + 1] * 0.125f) << 16);
        wj[e] = f2bf(pj[2 * e] * 0.125f) | (f2bf(pj[2 * e + 1] * 0.125f) << 16);
      }
      av.x = wi[0]; av.y = wi[1]; av.z = wi[2]; av.w = wi[3];
      bv.x = wj[0]; bv.y = wj[1]; bv.z = wj[2]; bv.w = wj[3];
    }
    lds[row * 8 + (ch ^ sw)] = av;
    lds[512 + row * 8 + (ch ^ sw)] = bv;
  }
  __syncthreads();

  const int tx = t & 15, ty = t >> 4;
  const int i0 = ty * 4, j0 = tx * 4;
  const int swi = ty & 7, swj = tx & 7;   // == (row>>2)&7 for our rows

  // ---- 4x4 micro-tile over 8 bf16x8 chunks ----
  float acc[4][4] = {};
#pragma unroll
  for (int dc = 0; dc < 8; ++dc) {
    uint4 ai[4], bj[4];
#pragma unroll
    for (int a = 0; a < 4; ++a) ai[a] = lds[(i0 + a) * 8 + (dc ^ swi)];
#pragma unroll
    for (int q = 0; q < 4; ++q)
      bj[q] = lds[512 + (j0 + q) * 8 + (dc ^ swj)];
    DOT_WORD(x)
    DOT_WORD(y)
    DOT_WORD(z)
    DOT_WORD(w)
  }

  // ---- f = exp(acc)*ci*cj ----
  const float* cbp = c + b * TT;
  float ci[4], cj[4];
#pragma unroll
  for (int a = 0; a < 4; ++a) ci[a] = cbp[gi0 + i0 + a];
#pragma unroll
  for (int q = 0; q < 4; ++q) cj[q] = cbp[gj0 + j0 + q];
#pragma unroll
  for (int a = 0; a < 4; ++a)
#pragma unroll
    for (int q = 0; q < 4; ++q)
      acc[a][q] = __expf(acc[a][q]) * ci[a] * cj[q];

  const size_t TTT = (size_t)TT * TT;
  const size_t obase = (size_t)b * TTT;

  // ---- mirror tile FIRST (off-diag): transpose via LDS, then store ----
  // (barriers here are fine: no global stores have been issued yet)
  if (!diag) {
    __syncthreads();   // bf16 panels dead
    float4* ftv = (float4*)lds;   // 64 rows (j) x 16 f4-chunks (i), 16 KB
#pragma unroll
    for (int q = 0; q < 4; ++q) {
      int jr = j0 + q;
      int sw = tx & 7;            // ((jr)>>2)&7 == tx&7
      ftv[jr * 16 + (ty ^ sw)] =
          make_float4(acc[0][q], acc[1][q], acc[2][q], acc[3][q]);
    }
    __syncthreads();
#pragma unroll
    for (int kk = 0; kk < 4; ++kk) {
      int idx = kk * 256 + t;
      int jr = idx >> 4, ch = idx & 15;
      int sw = (jr >> 2) & 7;
      float4 v = ftv[jr * 16 + (ch ^ sw)];
      size_t off = obase + (size_t)(gj0 + jr) * TT + gi0 + ch * 4;
      *reinterpret_cast<float4*>(out_f + off) = v;
      *reinterpret_cast<float4*>(out_y + off) = v;
    }
  }

  // ---- direct tile stores LAST (no barrier after; block exits draining) ----
#pragma unroll
  for (int a = 0; a < 4; ++a) {
    int gi = gi0 + i0 + a;
    float fv[4], yv[4];
#pragma unroll
    for (int q = 0; q < 4; ++q) {
      float ff = acc[a][q];
      float yy = ff;
      if (diag && (i0 + a == j0 + q)) {
        ff += JITTER;
        yy = ff + noise[b * TT + gi];
      }
      fv[q] = ff;
      yv[q] = yy;
    }
    size_t off = obase + (size_t)gi * TT + gj0 + j0;
    *reinterpret_cast<float4*>(out_f + off) =
        make_float4(fv[0], fv[1], fv[2], fv[3]);
    *reinterpret_cast<float4*>(out_y + off) =
        make_float4(yv[0], yv[1], yv[2], yv[3]);
  }
}

extern "C" void kernel_launch(void* const* d_in, const int* in_sizes, int n_in,
                              void* d_out, int out_size, void* d_ws,
                              size_t ws_size, hipStream_t stream) {
  const float* in = (const float*)d_in[0];
  float* out = (float*)d_out;
  float* c = (float*)d_ws;                               // BT floats
  float* noise = c + BT;                                 // BT floats
  uint4* zp4 = (uint4*)((char*)d_ws + (size_t)2 * BT * 4);  // BT*64 bf16 = 2MB
  float* out_mean = out;                                 // BT
  float* out_f = out + BT;                               // BB*TT*TT
  float* out_y = out_f + (size_t)BB * TT * TT;

  const size_t need = (size_t)2 * BT * 4 + (size_t)BT * DD * 2;
  if (ws_size >= need) {
    pack_stats_kernel<<<(BT * 8) / 256, 256, 0, stream>>>(in, out_mean, c,
                                                          noise, zp4);
    cov_kernel<true><<<NBLK, 256, 0, stream>>>(in, zp4, c, noise, out_f,
                                               out_y);
  } else {
    row_stats_kernel<<<BT / 256, 256, 0, stream>>>(in, out_mean, c, noise);
    cov_kernel<false><<<NBLK, 256, 0, stream>>>(in, zp4, c, noise, out_f,
                                                out_y);
  }
}

// Round 9
// 56.736 us; speedup vs baseline: 2.4073x; 1.0776x over previous
//
#include <hip/hip_runtime.h>
#include <math.h>

#define BB 8
#define TT 2048
#define FF 67
#define DD 64
#define BT (BB * TT)
#define JITTER 1e-6f

#define NT 32                  // 64-wide tiles per dim
#define NOFF 496               // strict-lower tiles per batch
#define NOFFB (BB * NOFF)      // 3968 off-diag blocks (first)
#define NBLK (NOFFB + BB * NT) // + 256 diag blocks (tail) = 4224

// ---- bf16 helpers (manual RNE pack) -----------------------------------------
__device__ __forceinline__ unsigned int f2bf(float f) {
  unsigned int u = __float_as_uint(f);
  return (u + 0x7fffu + ((u >> 16) & 1u)) >> 16;
}

// ---------------- kernel A: pack z->bf16 + per-row stats ---------------------
// 8 lanes per row; each packs 8 d's (d = dc*8..dc*8+7) into one uint4.
__global__ __launch_bounds__(256) void pack_stats_kernel(
    const float* __restrict__ in, float* __restrict__ out_mean,
    float* __restrict__ c, float* __restrict__ noise,
    uint4* __restrict__ zp4) {
  int g = blockIdx.x * 256 + threadIdx.x;   // 0 .. BT*8-1
  int row = g >> 3, dc = g & 7;
  const float* p = in + (size_t)row * FF + 1 + dc * 8;
  float sq = 0.f;
  unsigned int w[4];
#pragma unroll
  for (int k = 0; k < 4; ++k) {
    float a = p[2 * k] * 0.125f;
    float b2 = p[2 * k + 1] * 0.125f;
    sq += a * a + b2 * b2;
    w[k] = f2bf(a) | (f2bf(b2) << 16);
  }
  uint4 pk;
  pk.x = w[0]; pk.y = w[1]; pk.z = w[2]; pk.w = w[3];
  zp4[(size_t)row * 8 + dc] = pk;
  sq += __shfl_xor(sq, 1);
  sq += __shfl_xor(sq, 2);
  sq += __shfl_xor(sq, 4);
  if (dc == 0) {
    const float* r = in + (size_t)row * FF;
    out_mean[row] = r[0];
    float v = r[1 + DD];
    float x = r[1 + DD + 1];
    float sp = fmaxf(x, 0.f) + log1pf(__expf(-fabsf(x)));
    c[row] = v * __expf(-0.5f * sq);
    noise[row] = sp;
  }
}

// ---------------- fallback per-row stats (small ws) --------------------------
__global__ __launch_bounds__(256) void row_stats_kernel(
    const float* __restrict__ in, float* __restrict__ out_mean,
    float* __restrict__ c, float* __restrict__ noise) {
  int idx = blockIdx.x * 256 + threadIdx.x;
  if (idx >= BT) return;
  const float* row = in + (size_t)idx * FF;
  out_mean[idx] = row[0];
  float sq = 0.f;
#pragma unroll
  for (int d = 0; d < DD; ++d) {
    float z = row[1 + d] * 0.125f;
    sq = fmaf(z, z, sq);
  }
  float v = row[1 + DD];
  float x = row[1 + DD + 1];
  float sp = fmaxf(x, 0.f) + log1pf(__expf(-fabsf(x)));
  c[idx] = v * __expf(-0.5f * sq);
  noise[idx] = sp;
}

// packed bf16x2 dot: acc += a.lo*b.lo + a.hi*b.hi  (VOP3P v_dot2_f32_bf16)
#define DOT_WORD(WX)                                                      \
  _Pragma("unroll") for (int a = 0; a < 4; ++a)                           \
      _Pragma("unroll") for (int q = 0; q < 4; ++q)                       \
      asm("v_dot2_f32_bf16 %0, %1, %2, %0"                                \
          : "+v"(acc[a][q])                                               \
          : "v"(ai[a].WX), "v"(bj[q].WX));

// ---------------- kernel B: 64x64 tiles, bf16 panels, stores LAST ------------
// LDS 16 KB: bf16 A panel [0..511], B panel [512..1023] (uint4 units).
// After compute the f32 mirror tile (16 KB) aliases both panels. ALL barriers
// precede ALL global stores (compiler drains vmcnt at barriers -> a barrier
// after stores serializes store-drain per block; R4-R7's hidden cost).
template <bool PACKED>
__global__ __launch_bounds__(256, 4) void cov_kernel(
    const float* __restrict__ in, const uint4* __restrict__ zp4,
    const float* __restrict__ c, const float* __restrict__ noise,
    float* __restrict__ out_f, float* __restrict__ out_y) {
  __shared__ uint4 lds[1024];   // 16 KB

  // decode block -> (b, ti, tj); off-diag batch-major first, diag tail
  int wid = blockIdx.x;
  int b, ti, tj;
  if (wid < NOFFB) {
    b = wid / NOFF;
    int k = wid - b * NOFF;          // k = ti*(ti-1)/2 + tj, tj < ti
    int x = (int)((1.0f + sqrtf(1.0f + 8.0f * (float)k)) * 0.5f);
    while (x * (x - 1) / 2 > k) --x;
    while ((x + 1) * x / 2 <= k) ++x;
    ti = x;
    tj = k - x * (x - 1) / 2;
  } else {
    int r = wid - NOFFB;
    b = r >> 5;
    ti = tj = r & 31;
  }
  const bool diag = (ti == tj);
  const int gi0 = ti * 64, gj0 = tj * 64;
  const int t = threadIdx.x;

  // ---- stage bf16 panels; swizzle sw=(row>>2)&7 on 8-chunk index ----
#pragma unroll
  for (int kk = 0; kk < 2; ++kk) {
    int idx = kk * 256 + t;
    int row = idx >> 3, ch = idx & 7;
    int sw = (row >> 2) & 7;
    uint4 av, bv;
    if (PACKED) {
      av = zp4[(size_t)(b * TT + gi0 + row) * 8 + ch];
      bv = zp4[(size_t)(b * TT + gj0 + row) * 8 + ch];
    } else {
      const float* pi = in + (size_t)(b * TT + gi0 + row) * FF + 1 + ch * 8;
      const float* pj = in + (size_t)(b * TT + gj0 + row) * FF + 1 + ch * 8;
      unsigned int wi[4], wj[4];
#pragma unroll
      for (int e = 0; e < 4; ++e) {
        wi[e] = f2bf(pi[2 * e] * 0.125f) | (f2bf(pi[2 * e + 1] * 0.125f) << 16);
        wj[e] = f2bf(pj[2 * e] * 0.125f) | (f2bf(pj[2 * e + 1] * 0.125f) << 16);
      }
      av.x = wi[0]; av.y = wi[1]; av.z = wi[2]; av.w = wi[3];
      bv.x = wj[0]; bv.y = wj[1]; bv.z = wj[2]; bv.w = wj[3];
    }
    lds[row * 8 + (ch ^ sw)] = av;
    lds[512 + row * 8 + (ch ^ sw)] = bv;
  }
  __syncthreads();

  const int tx = t & 15, ty = t >> 4;
  const int i0 = ty * 4, j0 = tx * 4;
  const int swi = ty & 7, swj = tx & 7;   // == (row>>2)&7 for our rows

  // ---- 4x4 micro-tile over 8 bf16x8 chunks (packed dot2) ----
  float acc[4][4] = {};
#pragma unroll
  for (int dc = 0; dc < 8; ++dc) {
    uint4 ai[4], bj[4];
#pragma unroll
    for (int a = 0; a < 4; ++a) ai[a] = lds[(i0 + a) * 8 + (dc ^ swi)];
#pragma unroll
    for (int q = 0; q < 4; ++q)
      bj[q] = lds[512 + (j0 + q) * 8 + (dc ^ swj)];
    DOT_WORD(x)
    DOT_WORD(y)
    DOT_WORD(z)
    DOT_WORD(w)
  }

  // ---- f = exp(acc)*ci*cj ----
  const float* cbp = c + b * TT;
  float ci[4], cj[4];
#pragma unroll
  for (int a = 0; a < 4; ++a) ci[a] = cbp[gi0 + i0 + a];
#pragma unroll
  for (int q = 0; q < 4; ++q) cj[q] = cbp[gj0 + j0 + q];
#pragma unroll
  for (int a = 0; a < 4; ++a)
#pragma unroll
    for (int q = 0; q < 4; ++q)
      acc[a][q] = __expf(acc[a][q]) * ci[a] * cj[q];

  const size_t TTT = (size_t)TT * TT;
  const size_t obase = (size_t)b * TTT;

  // ---- mirror tile FIRST (off-diag): transpose via LDS, then store ----
  // (barriers here are fine: no global stores have been issued yet)
  if (!diag) {
    __syncthreads();   // bf16 panels dead
    float4* ftv = (float4*)lds;   // 64 rows (j) x 16 f4-chunks (i), 16 KB
#pragma unroll
    for (int q = 0; q < 4; ++q) {
      int jr = j0 + q;
      int sw = tx & 7;            // ((jr)>>2)&7 == tx&7
      ftv[jr * 16 + (ty ^ sw)] =
          make_float4(acc[0][q], acc[1][q], acc[2][q], acc[3][q]);
    }
    __syncthreads();
#pragma unroll
    for (int kk = 0; kk < 4; ++kk) {
      int idx = kk * 256 + t;
      int jr = idx >> 4, ch = idx & 15;
      int sw = (jr >> 2) & 7;
      float4 v = ftv[jr * 16 + (ch ^ sw)];
      size_t off = obase + (size_t)(gj0 + jr) * TT + gi0 + ch * 4;
      *reinterpret_cast<float4*>(out_f + off) = v;
      *reinterpret_cast<float4*>(out_y + off) = v;
    }
  }

  // ---- direct tile stores LAST (no barrier after; block exits draining) ----
#pragma unroll
  for (int a = 0; a < 4; ++a) {
    int gi = gi0 + i0 + a;
    float fv[4], yv[4];
#pragma unroll
    for (int q = 0; q < 4; ++q) {
      float ff = acc[a][q];
      float yy = ff;
      if (diag && (i0 + a == j0 + q)) {
        ff += JITTER;
        yy = ff + noise[b * TT + gi];
      }
      fv[q] = ff;
      yv[q] = yy;
    }
    size_t off = obase + (size_t)gi * TT + gj0 + j0;
    *reinterpret_cast<float4*>(out_f + off) =
        make_float4(fv[0], fv[1], fv[2], fv[3]);
    *reinterpret_cast<float4*>(out_y + off) =
        make_float4(yv[0], yv[1], yv[2], yv[3]);
  }
}

extern "C" void kernel_launch(void* const* d_in, const int* in_sizes, int n_in,
                              void* d_out, int out_size, void* d_ws,
                              size_t ws_size, hipStream_t stream) {
  const float* in = (const float*)d_in[0];
  float* out = (float*)d_out;
  float* c = (float*)d_ws;                               // BT floats
  float* noise = c + BT;                                 // BT floats
  uint4* zp4 = (uint4*)((char*)d_ws + (size_t)2 * BT * 4);  // BT*64 bf16 = 2MB
  float* out_mean = out;                                 // BT
  float* out_f = out + BT;                               // BB*TT*TT
  float* out_y = out_f + (size_t)BB * TT * TT;

  const size_t need = (size_t)2 * BT * 4 + (size_t)BT * DD * 2;
  if (ws_size >= need) {
    pack_stats_kernel<<<(BT * 8) / 256, 256, 0, stream>>>(in, out_mean, c,
                                                          noise, zp4);
    cov_kernel<true><<<NBLK, 256, 0, stream>>>(in, zp4, c, noise, out_f,
                                               out_y);
  } else {
    row_stats_kernel<<<BT / 256, 256, 0, stream>>>(in, out_mean, c, noise);
    cov_kernel<false><<<NBLK, 256, 0, stream>>>(in, zp4, c, noise, out_f,
                                                out_y);
  }
}

// Round 10
// 56.146 us; speedup vs baseline: 2.4327x; 1.0105x over previous
//
#include <hip/hip_runtime.h>
#include <math.h>

#define BB 8
#define TT 2048
#define FF 67
#define DD 64
#define BT (BB * TT)
#define JITTER 1e-6f

#define NT 32                  // 64-wide tiles per dim
#define NOFF 496               // strict-lower tiles per batch
#define NOFFB (BB * NOFF)      // 3968 off-diag blocks (first)
#define NBLK (NOFFB + BB * NT) // + 256 diag blocks (tail) = 4224 = 8*528
#define CPX (NBLK / 8)         // 528 blocks per XCD chunk

// ---- bf16 helpers (manual RNE pack) -----------------------------------------
__device__ __forceinline__ unsigned int f2bf(float f) {
  unsigned int u = __float_as_uint(f);
  return (u + 0x7fffu + ((u >> 16) & 1u)) >> 16;
}

// ---------------- kernel A: pack z->bf16 + per-row stats ---------------------
// 8 lanes per row; each packs 8 d's (d = dc*8..dc*8+7) into one uint4.
__global__ __launch_bounds__(256) void pack_stats_kernel(
    const float* __restrict__ in, float* __restrict__ out_mean,
    float* __restrict__ c, float* __restrict__ noise,
    uint4* __restrict__ zp4) {
  int g = blockIdx.x * 256 + threadIdx.x;   // 0 .. BT*8-1
  int row = g >> 3, dc = g & 7;
  const float* p = in + (size_t)row * FF + 1 + dc * 8;
  float sq = 0.f;
  unsigned int w[4];
#pragma unroll
  for (int k = 0; k < 4; ++k) {
    float a = p[2 * k] * 0.125f;
    float b2 = p[2 * k + 1] * 0.125f;
    sq += a * a + b2 * b2;
    w[k] = f2bf(a) | (f2bf(b2) << 16);
  }
  uint4 pk;
  pk.x = w[0]; pk.y = w[1]; pk.z = w[2]; pk.w = w[3];
  zp4[(size_t)row * 8 + dc] = pk;
  sq += __shfl_xor(sq, 1);
  sq += __shfl_xor(sq, 2);
  sq += __shfl_xor(sq, 4);
  if (dc == 0) {
    const float* r = in + (size_t)row * FF;
    out_mean[row] = r[0];
    float v = r[1 + DD];
    float x = r[1 + DD + 1];
    float sp = fmaxf(x, 0.f) + log1pf(__expf(-fabsf(x)));
    c[row] = v * __expf(-0.5f * sq);
    noise[row] = sp;
  }
}

// ---------------- fallback per-row stats (small ws) --------------------------
__global__ __launch_bounds__(256) void row_stats_kernel(
    const float* __restrict__ in, float* __restrict__ out_mean,
    float* __restrict__ c, float* __restrict__ noise) {
  int idx = blockIdx.x * 256 + threadIdx.x;
  if (idx >= BT) return;
  const float* row = in + (size_t)idx * FF;
  out_mean[idx] = row[0];
  float sq = 0.f;
#pragma unroll
  for (int d = 0; d < DD; ++d) {
    float z = row[1 + d] * 0.125f;
    sq = fmaf(z, z, sq);
  }
  float v = row[1 + DD];
  float x = row[1 + DD + 1];
  float sp = fmaxf(x, 0.f) + log1pf(__expf(-fabsf(x)));
  c[idx] = v * __expf(-0.5f * sq);
  noise[idx] = sp;
}

// packed bf16x2 dot: acc += a.lo*b.lo + a.hi*b.hi  (VOP3P v_dot2_f32_bf16)
#define DOT_WORD(WX)                                                      \
  _Pragma("unroll") for (int a = 0; a < 4; ++a)                           \
      _Pragma("unroll") for (int q = 0; q < 4; ++q)                       \
      asm("v_dot2_f32_bf16 %0, %1, %2, %0"                                \
          : "+v"(acc[a][q])                                               \
          : "v"(ai[a].WX), "v"(bj[q].WX));

// ---------------- kernel B: 64x64 tiles, bf16 panels, stores LAST ------------
// LDS 16 KB: bf16 A panel [0..511], B panel [512..1023] (uint4 units).
// After compute the f32 mirror tile (16 KB) aliases both panels. ALL barriers
// precede ALL global stores (compiler drains vmcnt at barriers).
// XCD-aware bijective swizzle: each XCD gets a contiguous run of tile indices
// so tj-adjacent tiles (adjacent 256B store runs of the same output rows)
// share one L2 -> write-combining into long HBM bursts + A-panel read reuse.
template <bool PACKED>
__global__ __launch_bounds__(256, 4) void cov_kernel(
    const float* __restrict__ in, const uint4* __restrict__ zp4,
    const float* __restrict__ c, const float* __restrict__ noise,
    float* __restrict__ out_f, float* __restrict__ out_y) {
  __shared__ uint4 lds[1024];   // 16 KB

  // hw bid -> XCD-chunked wid (bijective; 4224 = 8*528 exactly)
  int bid = blockIdx.x;
  int wid = (bid & 7) * CPX + (bid >> 3);

  // decode wid -> (b, ti, tj); off-diag batch-major first, diag tail
  int b, ti, tj;
  if (wid < NOFFB) {
    b = wid / NOFF;
    int k = wid - b * NOFF;          // k = ti*(ti-1)/2 + tj, tj < ti
    int x = (int)((1.0f + sqrtf(1.0f + 8.0f * (float)k)) * 0.5f);
    while (x * (x - 1) / 2 > k) --x;
    while ((x + 1) * x / 2 <= k) ++x;
    ti = x;
    tj = k - x * (x - 1) / 2;
  } else {
    int r = wid - NOFFB;
    b = r >> 5;
    ti = tj = r & 31;
  }
  const bool diag = (ti == tj);
  const int gi0 = ti * 64, gj0 = tj * 64;
  const int t = threadIdx.x;

  // ---- stage bf16 panels; swizzle sw=(row>>2)&7 on 8-chunk index ----
#pragma unroll
  for (int kk = 0; kk < 2; ++kk) {
    int idx = kk * 256 + t;
    int row = idx >> 3, ch = idx & 7;
    int sw = (row >> 2) & 7;
    uint4 av, bv;
    if (PACKED) {
      av = zp4[(size_t)(b * TT + gi0 + row) * 8 + ch];
      bv = zp4[(size_t)(b * TT + gj0 + row) * 8 + ch];
    } else {
      const float* pi = in + (size_t)(b * TT + gi0 + row) * FF + 1 + ch * 8;
      const float* pj = in + (size_t)(b * TT + gj0 + row) * FF + 1 + ch * 8;
      unsigned int wi[4], wj[4];
#pragma unroll
      for (int e = 0; e < 4; ++e) {
        wi[e] = f2bf(pi[2 * e] * 0.125f) | (f2bf(pi[2 * e + 1] * 0.125f) << 16);
        wj[e] = f2bf(pj[2 * e] * 0.125f) | (f2bf(pj[2 * e + 1] * 0.125f) << 16);
      }
      av.x = wi[0]; av.y = wi[1]; av.z = wi[2]; av.w = wi[3];
      bv.x = wj[0]; bv.y = wj[1]; bv.z = wj[2]; bv.w = wj[3];
    }
    lds[row * 8 + (ch ^ sw)] = av;
    lds[512 + row * 8 + (ch ^ sw)] = bv;
  }
  __syncthreads();

  const int tx = t & 15, ty = t >> 4;
  const int i0 = ty * 4, j0 = tx * 4;
  const int swi = ty & 7, swj = tx & 7;   // == (row>>2)&7 for our rows

  // ---- 4x4 micro-tile over 8 bf16x8 chunks (packed dot2) ----
  float acc[4][4] = {};
#pragma unroll
  for (int dc = 0; dc < 8; ++dc) {
    uint4 ai[4], bj[4];
#pragma unroll
    for (int a = 0; a < 4; ++a) ai[a] = lds[(i0 + a) * 8 + (dc ^ swi)];
#pragma unroll
    for (int q = 0; q < 4; ++q)
      bj[q] = lds[512 + (j0 + q) * 8 + (dc ^ swj)];
    DOT_WORD(x)
    DOT_WORD(y)
    DOT_WORD(z)
    DOT_WORD(w)
  }

  // ---- f = exp(acc)*ci*cj ----
  const float* cbp = c + b * TT;
  float ci[4], cj[4];
#pragma unroll
  for (int a = 0; a < 4; ++a) ci[a] = cbp[gi0 + i0 + a];
#pragma unroll
  for (int q = 0; q < 4; ++q) cj[q] = cbp[gj0 + j0 + q];
#pragma unroll
  for (int a = 0; a < 4; ++a)
#pragma unroll
    for (int q = 0; q < 4; ++q)
      acc[a][q] = __expf(acc[a][q]) * ci[a] * cj[q];

  const size_t TTT = (size_t)TT * TT;
  const size_t obase = (size_t)b * TTT;

  // ---- mirror tile FIRST (off-diag): transpose via LDS, then store ----
  if (!diag) {
    __syncthreads();   // bf16 panels dead
    float4* ftv = (float4*)lds;   // 64 rows (j) x 16 f4-chunks (i), 16 KB
#pragma unroll
    for (int q = 0; q < 4; ++q) {
      int jr = j0 + q;
      int sw = tx & 7;            // ((jr)>>2)&7 == tx&7
      ftv[jr * 16 + (ty ^ sw)] =
          make_float4(acc[0][q], acc[1][q], acc[2][q], acc[3][q]);
    }
    __syncthreads();
#pragma unroll
    for (int kk = 0; kk < 4; ++kk) {
      int idx = kk * 256 + t;
      int jr = idx >> 4, ch = idx & 15;
      int sw = (jr >> 2) & 7;
      float4 v = ftv[jr * 16 + (ch ^ sw)];
      size_t off = obase + (size_t)(gj0 + jr) * TT + gi0 + ch * 4;
      *reinterpret_cast<float4*>(out_f + off) = v;
      *reinterpret_cast<float4*>(out_y + off) = v;
    }
  }

  // ---- direct tile stores LAST (no barrier after; block exits draining) ----
#pragma unroll
  for (int a = 0; a < 4; ++a) {
    int gi = gi0 + i0 + a;
    float fv[4], yv[4];
#pragma unroll
    for (int q = 0; q < 4; ++q) {
      float ff = acc[a][q];
      float yy = ff;
      if (diag && (i0 + a == j0 + q)) {
        ff += JITTER;
        yy = ff + noise[b * TT + gi];
      }
      fv[q] = ff;
      yv[q] = yy;
    }
    size_t off = obase + (size_t)gi * TT + gj0 + j0;
    *reinterpret_cast<float4*>(out_f + off) =
        make_float4(fv[0], fv[1], fv[2], fv[3]);
    *reinterpret_cast<float4*>(out_y + off) =
        make_float4(yv[0], yv[1], yv[2], yv[3]);
  }
}

extern "C" void kernel_launch(void* const* d_in, const int* in_sizes, int n_in,
                              void* d_out, int out_size, void* d_ws,
                              size_t ws_size, hipStream_t stream) {
  const float* in = (const float*)d_in[0];
  float* out = (float*)d_out;
  float* c = (float*)d_ws;                               // BT floats
  float* noise = c + BT;                                 // BT floats
  uint4* zp4 = (uint4*)((char*)d_ws + (size_t)2 * BT * 4);  // BT*64 bf16 = 2MB
  float* out_mean = out;                                 // BT
  float* out_f = out + BT;                               // BB*TT*TT
  float* out_y = out_f + (size_t)BB * TT * TT;

  const size_t need = (size_t)2 * BT * 4 + (size_t)BT * DD * 2;
  if (ws_size >= need) {
    pack_stats_kernel<<<(BT * 8) / 256, 256, 0, stream>>>(in, out_mean, c,
                                                          noise, zp4);
    cov_kernel<true><<<NBLK, 256, 0, stream>>>(in, zp4, c, noise, out_f,
                                               out_y);
  } else {
    row_stats_kernel<<<BT / 256, 256, 0, stream>>>(in, out_mean, c, noise);
    cov_kernel<false><<<NBLK, 256, 0, stream>>>(in, zp4, c, noise, out_f,
                                                out_y);
  }
}